// Round 4
// baseline (54.723 us; speedup 1.0000x reference)
//
#include <hip/hip_runtime.h>
#include <hip/hip_bf16.h>

#define B_ 128
#define I_ 2048
#define O_ 2048
#define SEG 10
#define BK 32
#define KSLICE 1024
#define NST (KSLICE / BK)   // 32 k-steps per wave (half of K)
#define XTILE 8192          // x tile: 128 rows x 32 k x 2B bf16, swizzled
#define DCH 1280            // D chunk: 32 i x 10 j x 4B f32 (contiguous)
#define DLS 1408            // + 128 B w chunk (at offset DCH)

typedef __attribute__((ext_vector_type(8))) short bf16x8;
typedef __attribute__((ext_vector_type(4))) float f32x4;

static __device__ __forceinline__ unsigned short f2bf(float f) {
    unsigned u = __float_as_uint(f);
    u += 0x7FFFu + ((u >> 16) & 1u);
    return (unsigned short)(u >> 16);
}

#define GLDS16(SRC, DST) \
    __builtin_amdgcn_global_load_lds( \
        (const __attribute__((address_space(1))) unsigned*)(SRC), \
        (__attribute__((address_space(3))) unsigned*)(DST), 16, 0, 0)
#define GLDS4(SRC, DST) \
    __builtin_amdgcn_global_load_lds( \
        (const __attribute__((address_space(1))) unsigned*)(SRC), \
        (__attribute__((address_space(3))) unsigned*)(DST), 4, 0, 0)

// ---------------------------------------------------------------------------
// Prepass: x [128][2048] f32 -> xb: 64 tiles of [128 rows][32 k] bf16.
// Row stride 64 B; XOR swizzle: byte(row,kl) = row*64 + ((kl*2) ^ sw2(row)),
// sw2(row) = ((row>>1)&3)<<4  -> A-frag ds_read_b128 lands 2-way (free).
// ---------------------------------------------------------------------------
__global__ void xconv(const float* __restrict__ x, char* __restrict__ xb) {
    int idx = blockIdx.x * 256 + threadIdx.x;   // 0..32767, one 8-k chunk each
    int row = idx >> 8;                         // 0..127
    int c   = idx & 255;
    int k0  = c * 8;
    int tt  = k0 >> 5;                          // global tile 0..63
    int kl  = k0 & 31;

    const float* xp = x + (size_t)row * I_ + k0;
    float4 a = *reinterpret_cast<const float4*>(xp);
    float4 b = *reinterpret_cast<const float4*>(xp + 4);

    bf16x8 h;
    h[0] = (short)f2bf(a.x); h[1] = (short)f2bf(a.y);
    h[2] = (short)f2bf(a.z); h[3] = (short)f2bf(a.w);
    h[4] = (short)f2bf(b.x); h[5] = (short)f2bf(b.y);
    h[6] = (short)f2bf(b.z); h[7] = (short)f2bf(b.w);

    int sw = ((row >> 1) & 3) << 4;
    size_t off = (size_t)tt * XTILE + row * 64 + ((kl * 2) ^ sw);
    *reinterpret_cast<bf16x8*>(xb + off) = h;
}

// ---------------------------------------------------------------------------
// Main kernel: grid 512, 256 thr (4 waves). Block owns 4 o's.
// wave = (p = wave>>1: o-pair) x (s = wave&1: K-half). Each wave: 2 o's,
// K = s*1024..+1023, BK=32. A-frags shared across both o's (halves LDS reads).
// Split-K partials combined via LDS BEFORE relu epilogue.
// ---------------------------------------------------------------------------
__global__ __launch_bounds__(256, 2) void neuro_fused(
    const char*  __restrict__ xb,     // swizzled bf16 x tiles
    const float* __restrict__ ctx,    // [O_]
    const float* __restrict__ w,      // [O_, I_]
    const float* __restrict__ bias,   // [O_]
    const float* __restrict__ astro,  // [O_]
    const float* __restrict__ D,      // [O_, I_, SEG]
    float* __restrict__ out)          // [B_, O_]
{
    __shared__ __align__(16) char xs[2][2][XTILE];     // [slice][buf]  32 KiB
    __shared__ __align__(16) char dls[4][2][2][DLS];   // [wave][buf][oo] 22 KiB

    const int tid  = threadIdx.x;
    const int wave = tid >> 6;
    const int lane = tid & 63;
    const int p    = wave >> 1;   // o-pair within block
    const int s    = wave & 1;    // k-slice
    const int o0   = blockIdx.x * 4 + p * 2;
    const int col  = lane & 15;   // MFMA n-index
    const int g    = lane >> 4;   // k-group

    f32x4 acc[2][8];
#pragma unroll
    for (int oo = 0; oo < 2; ++oo)
#pragma unroll
        for (int m = 0; m < 8; ++m) acc[oo][m] = (f32x4){0.f, 0.f, 0.f, 0.f};

    // per-lane B-fragment addressing within a staged D chunk
    const int   fbase = (col < 10) ? col * 4 : DCH;
    const int   fstr  = (col < 10) ? 40 : 4;
    const float dmask = (col <= 10) ? 1.0f : 0.0f;
    const int   sw    = ((col >> 1) & 3) << 4;

    auto stage_x = [&](int t, int buf) {
        const char* src = xb + (size_t)(s * NST + t) * XTILE + p * 4096 + lane * 16;
        char* dst = &xs[s][buf][p * 4096];
#pragma unroll
        for (int c = 0; c < 4; ++c)
            GLDS16(src + c * 1024, dst + c * 1024);
    };

    auto stage_d = [&](int t, int buf) {
        const size_t krow = (size_t)(s * KSLICE + t * BK);
#pragma unroll
        for (int oo = 0; oo < 2; ++oo) {
            const char* srcD = (const char*)D + ((size_t)(o0 + oo) * (I_ * SEG) + krow * SEG) * 4;
            char* dst = &dls[wave][buf][oo][0];
            GLDS16(srcD + lane * 16, dst);
            GLDS4(srcD + 1024 + lane * 4, dst + 1024);
            const char* srcW = (const char*)w + ((size_t)(o0 + oo) * I_ + krow) * 4;
            if (lane < 32) GLDS4(srcW + lane * 4, dst + DCH);
        }
    };

    auto compute = [&](int buf) {
        const char* xbase = &xs[s][buf][0];
        bf16x8 af[8];
#pragma unroll
        for (int m = 0; m < 8; ++m)
            af[m] = *reinterpret_cast<const bf16x8*>(
                xbase + (m * 16 + col) * 64 + ((16 * g) ^ sw));
#pragma unroll
        for (int oo = 0; oo < 2; ++oo) {
            const char* fp = &dls[wave][buf][oo][0] + fbase + (8 * g) * fstr;
            bf16x8 bfrag;
#pragma unroll
            for (int e = 0; e < 8; ++e) {
                float v = *reinterpret_cast<const float*>(fp + e * fstr);
                bfrag[e] = (short)f2bf(v * dmask);
            }
#pragma unroll
            for (int m = 0; m < 8; ++m)
                acc[oo][m] = __builtin_amdgcn_mfma_f32_16x16x32_bf16(af[m], bfrag, acc[oo][m], 0, 0, 0);
        }
    };

    stage_x(0, 0);
    stage_d(0, 0);
    __syncthreads();

#pragma unroll 1
    for (int t = 0; t < NST; t += 2) {
        stage_x(t + 1, 1);              // t+1 <= 31 always
        stage_d(t + 1, 1);
        compute(0);
        __syncthreads();

        if (t + 2 < NST) {
            stage_x(t + 2, 0);
            stage_d(t + 2, 0);
        }
        compute(1);
        __syncthreads();
    }

    // --- split-K combine through LDS (before relu!) --------------------------
    float* cs = reinterpret_cast<float*>(&xs[0][0][0]);   // 32 KiB scratch
    if (s == 1) {
#pragma unroll
        for (int oo = 0; oo < 2; ++oo)
#pragma unroll
            for (int m = 0; m < 8; ++m)
                *reinterpret_cast<f32x4*>(cs + p * 4096 + (oo * 8 + m) * 256 + lane * 4) = acc[oo][m];
    }
    __syncthreads();
    if (s == 0) {
#pragma unroll
        for (int oo = 0; oo < 2; ++oo) {
            float am = astro[o0 + oo] * ctx[o0 + oo];
            am = 1.0f / (1.0f + __expf(-am));
            const float bo = bias[o0 + oo];
#pragma unroll
            for (int m = 0; m < 8; ++m) {
                f32x4 other = *reinterpret_cast<const f32x4*>(cs + p * 4096 + (oo * 8 + m) * 256 + lane * 4);
#pragma unroll
                for (int r = 0; r < 4; ++r) {
                    float v = acc[oo][m][r] + other[r];
                    float dend = (col < 10) ? fmaxf(v, 0.0f) : 0.0f;
#pragma unroll
                    for (int sh = 1; sh < 16; sh <<= 1)
                        dend += __shfl_xor(dend, sh, 64);
                    float lin = __shfl(v, (lane & 48) | 10, 64);
                    if (col == 0) {
                        int b = m * 16 + g * 4 + r;
                        out[(size_t)b * O_ + (o0 + oo)] = dend + am * lin + bo;
                    }
                }
            }
        }
    }
}

extern "C" void kernel_launch(void* const* d_in, const int* in_sizes, int n_in,
                              void* d_out, int out_size, void* d_ws, size_t ws_size,
                              hipStream_t stream) {
    const float* x     = (const float*)d_in[0];
    const float* ctx   = (const float*)d_in[1];
    // d_in[2] = prev_activation (unused by the reference output)
    const float* w     = (const float*)d_in[3];
    const float* bias  = (const float*)d_in[4];
    const float* astro = (const float*)d_in[5];
    const float* D     = (const float*)d_in[6];
    float* out = (float*)d_out;
    char* xb = (char*)d_ws;   // 512 KiB swizzled bf16 x

    xconv<<<dim3(128), dim3(256), 0, stream>>>(x, xb);
    neuro_fused<<<dim3(512), dim3(256), 0, stream>>>(xb, ctx, w, bias, astro, D, out);
}